// Round 1
// baseline (178.839 us; speedup 1.0000x reference)
//
#include <hip/hip_runtime.h>

typedef __bf16 bf16x8 __attribute__((ext_vector_type(8)));
typedef float f32x4 __attribute__((ext_vector_type(4)));

__device__ __forceinline__ unsigned short f2bf(float f) {
  union { float f; unsigned u; } v; v.f = f;
  unsigned u = v.u;
  return (unsigned short)((u + 0x7fffu + ((u >> 16) & 1u)) >> 16);  // RNE
}
__device__ __forceinline__ unsigned short f2bf_fast(float f) {
  union { float f; unsigned u; } v; v.f = f;
  return (unsigned short)((v.u + 0x8000u) >> 16);  // round-half-up, for P only
}
__device__ __forceinline__ void gload_lds16(const void* g, void* l) {
  __builtin_amdgcn_global_load_lds(
      (const __attribute__((address_space(1))) unsigned int*)g,
      (__attribute__((address_space(3))) unsigned int*)l, 16, 0, 0);
}
__device__ __forceinline__ void cvt4(const float* __restrict__ s,
                                     unsigned short* __restrict__ d, int u) {
  f32x4 v = ((const f32x4*)s)[u];
  union { unsigned short s[4]; unsigned long long u; } o;
  o.s[0] = f2bf(v[0]); o.s[1] = f2bf(v[1]); o.s[2] = f2bf(v[2]); o.s[3] = f2bf(v[3]);
  ((unsigned long long*)d)[u] = o.u;
}

// LDS tile swizzle (128B rows): row r, 16B-chunk c stored at position c^(r&7).
// Staging lane fetches global chunk (ln&7)^(ln>>3); reads XOR chunk with lq&7.
// For 256B rows (BK=128): chunk c (0..15) at position (c&8)|((c&7)^(r&7)).

// ---------------- prep: f32->bf16 conversions + ebj, one launch -------------
__global__ void prep(const float* __restrict__ x, const float* __restrict__ W1,
                     const float* __restrict__ Wv, const float* __restrict__ Wp,
                     const float* __restrict__ w2, const float* __restrict__ b2,
                     unsigned short* __restrict__ xb, unsigned short* __restrict__ W1b,
                     unsigned short* __restrict__ Wvb, unsigned short* __restrict__ Wpb,
                     unsigned short* __restrict__ w2t, unsigned short* __restrict__ ebj) {
  int u = blockIdx.x * 256 + threadIdx.x;
  if (u < 1048576) { cvt4(x, xb, u); return; }
  u -= 1048576;
  if (u < 262144) { cvt4(W1, W1b, u); return; }
  u -= 262144;
  if (u < 262144) { cvt4(Wv, Wvb, u); return; }
  u -= 262144;
  if (u < 262144) { cvt4(Wp, Wpb, u); return; }
  u -= 262144;
  if (u < 32768) {
    // w2 (64,2048) f32 -> w2t (2048,64) bf16
    int j = u >> 4, d4 = (u & 15) * 4;
    union { unsigned short s[4]; unsigned long long x; } o;
#pragma unroll
    for (int i = 0; i < 4; ++i) o.s[i] = f2bf(w2[(d4 + i) * 2048 + j]);
    ((unsigned long long*)w2t)[u] = o.x;
    return;
  }
  u -= 32768;
  // ebj = bf16(exp(b2)), 2048 elems in 512 x4-units
  union { unsigned short s[4]; unsigned long long x; } o;
#pragma unroll
  for (int i = 0; i < 4; ++i) o.s[i] = f2bf(__expf(b2[u * 4 + i]));
  ((unsigned long long*)ebj)[u] = o.x;
}

// ---------------- fused r & vt GEMM: 64-token blocks, 4/CU ------------------
__global__ __launch_bounds__(256) void gemm_rv(
    const unsigned short* __restrict__ xb, const unsigned short* __restrict__ W1b,
    const unsigned short* __restrict__ Wvb, const float* __restrict__ b1,
    const float* __restrict__ bv, const float* __restrict__ b2,
    unsigned short* __restrict__ rb, unsigned short* __restrict__ vtb) {
  __shared__ unsigned short Xs[64 * 64];
  __shared__ unsigned short W1s[64 * 64];
  __shared__ unsigned short Wvs[64 * 64];
  const int tm = blockIdx.x * 64, n0 = blockIdx.y * 64;
  const int tid = threadIdx.x;
  const int wv = tid >> 6, ln = tid & 63;
  const int quad = ln >> 4, lq = ln & 15;
  const int rowL = ln >> 3;
  const int kc = (((ln & 7) ^ rowL) & 7) * 8;
  const int sx = lq & 7;
  const int ko0 = (quad ^ sx) * 8, ko1 = ((4 + quad) ^ sx) * 8;

  f32x4 accR[4], accV[4];
  const f32x4 zf = {0.f, 0.f, 0.f, 0.f};
#pragma unroll
  for (int j = 0; j < 4; ++j) { accR[j] = zf; accV[j] = zf; }

  for (int k0 = 0; k0 < 1024; k0 += 64) {
    __syncthreads();
#pragma unroll
    for (int l = 0; l < 2; ++l) {
      int row = l * 32 + wv * 8 + rowL;
      gload_lds16(xb + (tm + row) * 1024 + k0 + kc, &Xs[l * 2048 + wv * 512]);
      gload_lds16(W1b + (n0 + row) * 1024 + k0 + kc, &W1s[l * 2048 + wv * 512]);
      gload_lds16(Wvb + (n0 + row) * 1024 + k0 + kc, &Wvs[l * 2048 + wv * 512]);
    }
    __syncthreads();
#pragma unroll
    for (int kk = 0; kk < 2; ++kk) {
      const int ko = kk ? ko1 : ko0;
      bf16x8 xa  = *(const bf16x8*)&Xs[(wv * 16 + lq) * 64 + ko];
      bf16x8 wva = *(const bf16x8*)&Wvs[(wv * 16 + lq) * 64 + ko];
#pragma unroll
      for (int ni = 0; ni < 4; ++ni) {
        bf16x8 w1f = *(const bf16x8*)&W1s[(ni * 16 + lq) * 64 + ko];
        accR[ni] = __builtin_amdgcn_mfma_f32_16x16x32_bf16(xa, w1f, accR[ni], 0, 0, 0);
      }
#pragma unroll
      for (int nj = 0; nj < 4; ++nj) {
        bf16x8 xbf = *(const bf16x8*)&Xs[(nj * 16 + lq) * 64 + ko];
        accV[nj] = __builtin_amdgcn_mfma_f32_16x16x32_bf16(wva, xbf, accV[nj], 0, 0, 0);
      }
    }
  }
#pragma unroll
  for (int ni = 0; ni < 4; ++ni) {
    int col = n0 + ni * 16 + lq;
    float bc = b1[col];
#pragma unroll
    for (int rg = 0; rg < 4; ++rg) {
      int row = tm + wv * 16 + quad * 4 + rg;
      float v = accR[ni][rg] + bc;
      rb[row * 1024 + col] = f2bf(v > 0.f ? v : 0.f);
    }
  }
  float bvv[4];
#pragma unroll
  for (int rg = 0; rg < 4; ++rg) bvv[rg] = bv[n0 + wv * 16 + quad * 4 + rg];
#pragma unroll
  for (int nj = 0; nj < 4; ++nj) {
    int tok = tm + nj * 16 + lq;
    float eb = __expf(b2[tok & 2047]);
#pragma unroll
    for (int rg = 0; rg < 4; ++rg) {
      int ch = n0 + wv * 16 + quad * 4 + rg;
      vtb[ch * 4096 + tok] = f2bf((accV[nj][rg] + bvv[rg]) * eb);
    }
  }
}

// ---------------- final GEMM: d_out = yb @ Wp^T + bp (f32 out) --------------
__global__ __launch_bounds__(256) void gemm_p(
    const unsigned short* __restrict__ A, const unsigned short* __restrict__ Bt,
    const float* __restrict__ bias, float* __restrict__ C) {
  __shared__ unsigned short As[64 * 128];
  __shared__ unsigned short Bs[64 * 128];
  const int tid = threadIdx.x;
  const int wv = tid >> 6, ln = tid & 63;
  const int quad = ln >> 4, lq = ln & 15;
  const int tileM = blockIdx.y * 64, tileN = blockIdx.x * 64;
  const int srow = ln >> 4, pos = ln & 15;

  f32x4 acc[4];
  const f32x4 zf = {0.f, 0.f, 0.f, 0.f};
#pragma unroll
  for (int j = 0; j < 4; ++j) acc[j] = zf;

  int kof[4];
#pragma unroll
  for (int kk = 0; kk < 4; ++kk) {
    int c = kk * 4 + quad;
    kof[kk] = (((c & 8) | ((c & 7) ^ (lq & 7)))) * 8;
  }

  for (int k0 = 0; k0 < 1024; k0 += 128) {
    __syncthreads();
#pragma unroll
    for (int l = 0; l < 4; ++l) {
      int row = l * 16 + wv * 4 + srow;
      int cs = (pos & 8) | ((pos & 7) ^ (row & 7));
      gload_lds16(A + (tileM + row) * 1024 + k0 + cs * 8, &As[(l * 16 + wv * 4) * 128]);
      gload_lds16(Bt + (tileN + row) * 1024 + k0 + cs * 8, &Bs[(l * 16 + wv * 4) * 128]);
    }
    __syncthreads();
#pragma unroll
    for (int kk = 0; kk < 4; ++kk) {
      const int ko = kof[kk];
      bf16x8 af = *(const bf16x8*)&As[(wv * 16 + lq) * 128 + ko];
#pragma unroll
      for (int ni = 0; ni < 4; ++ni) {
        bf16x8 bfr = *(const bf16x8*)&Bs[(ni * 16 + lq) * 128 + ko];
        acc[ni] = __builtin_amdgcn_mfma_f32_16x16x32_bf16(af, bfr, acc[ni], 0, 0, 0);
      }
    }
  }
#pragma unroll
  for (int ni = 0; ni < 4; ++ni) {
    int col = tileN + ni * 16 + lq;
#pragma unroll
    for (int rg = 0; rg < 4; ++rg) {
      int row = tileM + wv * 16 + quad * 4 + rg;
      C[row * 1024 + col] = acc[ni][rg] + bias[col];
    }
  }
}

// ---------------- fused synthesizer attention, software-pipelined -----------
// Same pair decomposition as before (tiles (p,31-p) share one j-loop), but PV
// now runs ONE interval BEHIND S: iteration jt does PV(jt-1) from last
// interval's per-wave P (in LDS, already drained by the barrier) while S(jt)'s
// frag-read -> MFMA -> exp chain is in flight.  This removes the serial
// S->exp->Pstore->lgkm->Pload->PV chain from the critical path (it gets a full
// interval of slack).  V is 3-buffered so stage(jt+1) never collides with
// PV(jt-1)'s buffer ((jt+1)%3 != (jt-1)%3); W2 stays 2-buffered (only read in
// its own interval).  P is single-buffered per tile: per-wave-private LDS is
// in-order, and reads of P(jt-1) precede writes of P(jt) in program order.
// LDS = 16+24+16 = 56KB -> still 2 blocks/CU.  s_setprio(1) wraps both MFMA
// clusters (two independent blocks/CU at different phases -> T5 applies).
__global__ __launch_bounds__(256, 2) void attn(
    const unsigned short* __restrict__ r, const unsigned short* __restrict__ w2t,
    const unsigned short* __restrict__ vt, const unsigned short* __restrict__ ebj,
    unsigned short* __restrict__ y) {
  __shared__ unsigned short W2s[2][64 * 64];
  __shared__ unsigned short Vs[3][64 * 64];
  __shared__ unsigned short Ps[2][4][16 * 64];

  const int tid = threadIdx.x;
  const int wv = tid >> 6, ln = tid & 63;
  const int quad = ln >> 4, lq = ln & 15;
  const int bh = blockIdx.x, b = bh >> 4, h = bh & 15;
  const int q = blockIdx.y;
  const int p = (q < 8) ? q : 23 - q;             // pair (p, 31-p)
  const int ta = p, tb = 31 - p;
  const int t0a = ta * 64, t0b = tb * 64;
  const int rowL = ln >> 3;
  const int kc = (((ln & 7) ^ rowL) & 7) * 8;
  const int sx = lq & 7;
  const int ko0 = (quad ^ sx) * 8, ko1 = ((4 + quad) ^ sx) * 8;

  // R A-fragments for both tiles (L2-hot)
  bf16x8 ra[2][2];
  {
    const unsigned short* base = r + (b * 2048 + wv * 16 + lq) * 1024 + h * 64 + quad * 8;
    ra[0][0] = *(const bf16x8*)(base + t0a * 1024);
    ra[0][1] = *(const bf16x8*)(base + t0a * 1024 + 32);
    ra[1][0] = *(const bf16x8*)(base + t0b * 1024);
    ra[1][1] = *(const bf16x8*)(base + t0b * 1024 + 32);
  }

  f32x4 accY[2][4];
  f32x4 accL[2];
  const f32x4 zf = {0.f, 0.f, 0.f, 0.f};
#pragma unroll
  for (int s = 0; s < 2; ++s) {
    accL[s] = zf;
#pragma unroll
    for (int nd = 0; nd < 4; ++nd) accY[s][nd] = zf;
  }

  auto stage = [&](int jt) {
    int j0 = jt * 64;
    unsigned short* W2d = &W2s[jt & 1][0];
    unsigned short* Vd = &Vs[jt % 3][0];
#pragma unroll
    for (int l = 0; l < 2; ++l) {
      int row = l * 32 + wv * 8 + rowL;
      gload_lds16(w2t + (j0 + row) * 64 + kc, W2d + l * 2048 + wv * 512);
      gload_lds16(vt + (h * 64 + row) * 4096 + b * 2048 + j0 + kc,
                  Vd + l * 2048 + wv * 512);
    }
  };

#define PV(S, VB, EB0, EB1)                                                     \
    {                                                                           \
      _Pragma("unroll") for (int kk = 0; kk < 2; ++kk) {                        \
        const int ko = kk ? ko1 : ko0;                                          \
        bf16x8 pa = *(const bf16x8*)&Ps[S][wv][lq * 64 + ko];                   \
        _Pragma("unroll") for (int nd = 0; nd < 4; ++nd) {                      \
          bf16x8 bb = *(const bf16x8*)&Vs[VB][(nd * 16 + lq) * 64 + ko];        \
          accY[S][nd] = __builtin_amdgcn_mfma_f32_16x16x32_bf16(pa, bb, accY[S][nd], 0, 0, 0); \
        }                                                                       \
        accL[S] = __builtin_amdgcn_mfma_f32_16x16x32_bf16(pa, kk ? (EB1) : (EB0), accL[S], 0, 0, 0); \
      }                                                                         \
    }

#define EXPSTORE(S, SV, T0, TT)                                                 \
    {                                                                           \
      const bool diag = (jt == (TT));                                           \
      _Pragma("unroll") for (int ni = 0; ni < 4; ++ni) {                        \
        int j = j0 + ni * 16 + lq;                                              \
        _Pragma("unroll") for (int rg = 0; rg < 4; ++rg) {                      \
          float pe = __expf(SV[ni][rg]);                                        \
          if (diag) {                                                           \
            int t = (T0) + wv * 16 + quad * 4 + rg;                             \
            pe = (j <= t) ? pe : 0.f;                                           \
          }                                                                     \
          Ps[S][wv][(quad * 4 + rg) * 64 +                                      \
                    (((ni * 2 + (lq >> 3)) ^ ((quad * 4 + rg) & 7)) * 8) + (lq & 7)] = f2bf_fast(pe); \
        }                                                                       \
      }                                                                         \
    }

#define WRITEOUT(S, T0)                                                         \
    {                                                                           \
      float inv[4];                                                             \
      _Pragma("unroll") for (int rg = 0; rg < 4; ++rg)                          \
        inv[rg] = __builtin_amdgcn_rcpf(accL[S][rg]);                           \
      _Pragma("unroll") for (int nd = 0; nd < 4; ++nd)                          \
        _Pragma("unroll") for (int rg = 0; rg < 4; ++rg) {                      \
          int t = (T0) + wv * 16 + quad * 4 + rg;                               \
          y[(b * 2048 + t) * 1024 + h * 64 + nd * 16 + lq] =                    \
              f2bf(accY[S][nd][rg] * inv[rg]);                                  \
        }                                                                       \
    }

  stage(0);

  for (int jt = 0; jt <= tb + 1; ++jt) {
    const int pj = jt - 1;
    const bool doS = (jt <= tb);
    const bool doSa = (jt <= ta);

    if (doS) {
      __syncthreads();               // stage(jt) landed; P(jt-1) drained
      if (jt < tb) stage(jt + 1);
    }

    // ---- PV for pj: independent of this interval's S chain ----
    if (pj >= 0) {
      const int vb = pj % 3;
      const int j0p = pj * 64;
      bf16x8 eb0 = *(const bf16x8*)&ebj[j0p + quad * 8];
      bf16x8 eb1 = *(const bf16x8*)&ebj[j0p + 32 + quad * 8];
      __builtin_amdgcn_s_setprio(1);
      if (pj <= ta) PV(0, vb, eb0, eb1);
      PV(1, vb, eb0, eb1);
      __builtin_amdgcn_s_setprio(0);
    }

    // ---- S for jt: scores -> exp -> P store (consumed NEXT iteration) ----
    if (doS) {
      const int wb = jt & 1;
      const int j0 = jt * 64;
      bf16x8 w2f0[4], w2f1[4];
#pragma unroll
      for (int ni = 0; ni < 4; ++ni) {
        w2f0[ni] = *(const bf16x8*)&W2s[wb][(ni * 16 + lq) * 64 + ko0];
        w2f1[ni] = *(const bf16x8*)&W2s[wb][(ni * 16 + lq) * 64 + ko1];
      }
      f32x4 sv0[4], sv1[4];
      __builtin_amdgcn_s_setprio(1);
      if (doSa) {
#pragma unroll
        for (int ni = 0; ni < 4; ++ni) {
          sv0[ni] = __builtin_amdgcn_mfma_f32_16x16x32_bf16(ra[0][0], w2f0[ni], zf, 0, 0, 0);
          sv0[ni] = __builtin_amdgcn_mfma_f32_16x16x32_bf16(ra[0][1], w2f1[ni], sv0[ni], 0, 0, 0);
        }
      }
#pragma unroll
      for (int ni = 0; ni < 4; ++ni) {
        sv1[ni] = __builtin_amdgcn_mfma_f32_16x16x32_bf16(ra[1][0], w2f0[ni], zf, 0, 0, 0);
        sv1[ni] = __builtin_amdgcn_mfma_f32_16x16x32_bf16(ra[1][1], w2f1[ni], sv1[ni], 0, 0, 0);
      }
      __builtin_amdgcn_s_setprio(0);
      if (doSa) EXPSTORE(0, sv0, t0a, ta);
      EXPSTORE(1, sv1, t0b, tb);
    }

    if (pj == ta) WRITEOUT(0, t0a);
    if (pj == tb) WRITEOUT(1, t0b);
  }
#undef PV
#undef EXPSTORE
#undef WRITEOUT
}

// ---------------- launch ----------------
extern "C" void kernel_launch(void* const* d_in, const int* in_sizes, int n_in,
                              void* d_out, int out_size, void* d_ws, size_t ws_size,
                              hipStream_t stream) {
  const float* x  = (const float*)d_in[0];
  const float* W1 = (const float*)d_in[1];
  const float* b1 = (const float*)d_in[2];
  const float* w2 = (const float*)d_in[3];
  const float* b2 = (const float*)d_in[4];
  const float* Wv = (const float*)d_in[5];
  const float* bv = (const float*)d_in[6];
  const float* Wp = (const float*)d_in[7];
  const float* bp = (const float*)d_in[8];

  unsigned short* ws  = (unsigned short*)d_ws;
  unsigned short* xb   = ws;                 // 4096x1024 bf16
  unsigned short* W1b  = ws + 4194304;       // 1024x1024
  unsigned short* Wvb  = ws + 5242880;       // 1024x1024
  unsigned short* Wpb  = ws + 6291456;       // 1024x1024
  unsigned short* w2t  = ws + 7340032;       // 2048x64
  unsigned short* rb   = ws + 7471104;       // 4096x1024
  unsigned short* vt   = ws + 11665408;      // 1024x4096
  unsigned short* yb   = ws + 15859712;      // 4096x1024 bf16
  unsigned short* ebjb = ws + 20054016;      // 2048 bf16

  prep<<<7298, 256, 0, stream>>>(x, W1, Wv, Wp, w2, b2, xb, W1b, Wvb, Wpb, w2t, ebjb);
  gemm_rv<<<dim3(64, 16), 256, 0, stream>>>(xb, W1b, Wvb, b1, bv, b2, rb, vt);
  attn<<<dim3(32, 16), 256, 0, stream>>>(rb, w2t, vt, ebjb, yb);
  gemm_p<<<dim3(16, 64), 256, 0, stream>>>(yb, Wpb, bp, (float*)d_out);
}

// Round 2
// 166.783 us; speedup vs baseline: 1.0723x; 1.0723x over previous
//
#include <hip/hip_runtime.h>

typedef __bf16 bf16x8 __attribute__((ext_vector_type(8)));
typedef float f32x4 __attribute__((ext_vector_type(4)));

__device__ __forceinline__ unsigned short f2bf(float f) {
  union { float f; unsigned u; } v; v.f = f;
  unsigned u = v.u;
  return (unsigned short)((u + 0x7fffu + ((u >> 16) & 1u)) >> 16);  // RNE
}
__device__ __forceinline__ void gload_lds16(const void* g, void* l) {
  __builtin_amdgcn_global_load_lds(
      (const __attribute__((address_space(1))) unsigned int*)g,
      (__attribute__((address_space(3))) unsigned int*)l, 16, 0, 0);
}
__device__ __forceinline__ unsigned cvtpk(float lo, float hi) {
  unsigned r;
  asm("v_cvt_pk_bf16_f32 %0, %1, %2" : "=v"(r) : "v"(lo), "v"(hi));
  return r;
}
__device__ __forceinline__ void cvt4(const float* __restrict__ s,
                                     unsigned short* __restrict__ d, int u) {
  f32x4 v = ((const f32x4*)s)[u];
  union { unsigned short s[4]; unsigned long long u; } o;
  o.s[0] = f2bf(v[0]); o.s[1] = f2bf(v[1]); o.s[2] = f2bf(v[2]); o.s[3] = f2bf(v[3]);
  ((unsigned long long*)d)[u] = o.u;
}

// LDS tile swizzle (128B rows): row r, 16B-chunk c stored at position c^(r&7).
// Staging lane fetches global chunk (ln&7)^(ln>>3); reads XOR chunk with lq&7.
// For 256B rows (BK=128): chunk c (0..15) at position (c&8)|((c&7)^(r&7)).

// ---------------- prep: f32->bf16 conversions + ebj, one launch -------------
__global__ void prep(const float* __restrict__ x, const float* __restrict__ W1,
                     const float* __restrict__ Wv, const float* __restrict__ Wp,
                     const float* __restrict__ w2, const float* __restrict__ b2,
                     unsigned short* __restrict__ xb, unsigned short* __restrict__ W1b,
                     unsigned short* __restrict__ Wvb, unsigned short* __restrict__ Wpb,
                     unsigned short* __restrict__ w2t, unsigned short* __restrict__ ebj) {
  int u = blockIdx.x * 256 + threadIdx.x;
  if (u < 1048576) { cvt4(x, xb, u); return; }
  u -= 1048576;
  if (u < 262144) { cvt4(W1, W1b, u); return; }
  u -= 262144;
  if (u < 262144) { cvt4(Wv, Wvb, u); return; }
  u -= 262144;
  if (u < 262144) { cvt4(Wp, Wpb, u); return; }
  u -= 262144;
  if (u < 32768) {
    // w2 (64,2048) f32 -> w2t (2048,64) bf16
    int j = u >> 4, d4 = (u & 15) * 4;
    union { unsigned short s[4]; unsigned long long x; } o;
#pragma unroll
    for (int i = 0; i < 4; ++i) o.s[i] = f2bf(w2[(d4 + i) * 2048 + j]);
    ((unsigned long long*)w2t)[u] = o.x;
    return;
  }
  u -= 32768;
  // ebj = bf16(exp(b2)), 2048 elems in 512 x4-units
  union { unsigned short s[4]; unsigned long long x; } o;
#pragma unroll
  for (int i = 0; i < 4; ++i) o.s[i] = f2bf(__expf(b2[u * 4 + i]));
  ((unsigned long long*)ebj)[u] = o.x;
}

// ---------------- fused r & vt GEMM: 64-token blocks, 4/CU ------------------
__global__ __launch_bounds__(256) void gemm_rv(
    const unsigned short* __restrict__ xb, const unsigned short* __restrict__ W1b,
    const unsigned short* __restrict__ Wvb, const float* __restrict__ b1,
    const float* __restrict__ bv, const float* __restrict__ b2,
    unsigned short* __restrict__ rb, unsigned short* __restrict__ vtb) {
  __shared__ unsigned short Xs[64 * 64];
  __shared__ unsigned short W1s[64 * 64];
  __shared__ unsigned short Wvs[64 * 64];
  const int tm = blockIdx.x * 64, n0 = blockIdx.y * 64;
  const int tid = threadIdx.x;
  const int wv = tid >> 6, ln = tid & 63;
  const int quad = ln >> 4, lq = ln & 15;
  const int rowL = ln >> 3;
  const int kc = (((ln & 7) ^ rowL) & 7) * 8;
  const int sx = lq & 7;
  const int ko0 = (quad ^ sx) * 8, ko1 = ((4 + quad) ^ sx) * 8;

  f32x4 accR[4], accV[4];
  const f32x4 zf = {0.f, 0.f, 0.f, 0.f};
#pragma unroll
  for (int j = 0; j < 4; ++j) { accR[j] = zf; accV[j] = zf; }

  for (int k0 = 0; k0 < 1024; k0 += 64) {
    __syncthreads();
#pragma unroll
    for (int l = 0; l < 2; ++l) {
      int row = l * 32 + wv * 8 + rowL;
      gload_lds16(xb + (tm + row) * 1024 + k0 + kc, &Xs[l * 2048 + wv * 512]);
      gload_lds16(W1b + (n0 + row) * 1024 + k0 + kc, &W1s[l * 2048 + wv * 512]);
      gload_lds16(Wvb + (n0 + row) * 1024 + k0 + kc, &Wvs[l * 2048 + wv * 512]);
    }
    __syncthreads();
#pragma unroll
    for (int kk = 0; kk < 2; ++kk) {
      const int ko = kk ? ko1 : ko0;
      bf16x8 xa  = *(const bf16x8*)&Xs[(wv * 16 + lq) * 64 + ko];
      bf16x8 wva = *(const bf16x8*)&Wvs[(wv * 16 + lq) * 64 + ko];
#pragma unroll
      for (int ni = 0; ni < 4; ++ni) {
        bf16x8 w1f = *(const bf16x8*)&W1s[(ni * 16 + lq) * 64 + ko];
        accR[ni] = __builtin_amdgcn_mfma_f32_16x16x32_bf16(xa, w1f, accR[ni], 0, 0, 0);
      }
#pragma unroll
      for (int nj = 0; nj < 4; ++nj) {
        bf16x8 xbf = *(const bf16x8*)&Xs[(nj * 16 + lq) * 64 + ko];
        accV[nj] = __builtin_amdgcn_mfma_f32_16x16x32_bf16(wva, xbf, accV[nj], 0, 0, 0);
      }
    }
  }
#pragma unroll
  for (int ni = 0; ni < 4; ++ni) {
    int col = n0 + ni * 16 + lq;
    float bc = b1[col];
#pragma unroll
    for (int rg = 0; rg < 4; ++rg) {
      int row = tm + wv * 16 + quad * 4 + rg;
      float v = accR[ni][rg] + bc;
      rb[row * 1024 + col] = f2bf(v > 0.f ? v : 0.f);
    }
  }
  float bvv[4];
#pragma unroll
  for (int rg = 0; rg < 4; ++rg) bvv[rg] = bv[n0 + wv * 16 + quad * 4 + rg];
#pragma unroll
  for (int nj = 0; nj < 4; ++nj) {
    int tok = tm + nj * 16 + lq;
    float eb = __expf(b2[tok & 2047]);
#pragma unroll
    for (int rg = 0; rg < 4; ++rg) {
      int ch = n0 + wv * 16 + quad * 4 + rg;
      vtb[ch * 4096 + tok] = f2bf((accV[nj][rg] + bvv[rg]) * eb);
    }
  }
}

// ---------------- final GEMM: d_out = yb @ Wp^T + bp (f32 out) --------------
__global__ __launch_bounds__(256) void gemm_p(
    const unsigned short* __restrict__ A, const unsigned short* __restrict__ Bt,
    const float* __restrict__ bias, float* __restrict__ C) {
  __shared__ unsigned short As[64 * 128];
  __shared__ unsigned short Bs[64 * 128];
  const int tid = threadIdx.x;
  const int wv = tid >> 6, ln = tid & 63;
  const int quad = ln >> 4, lq = ln & 15;
  const int tileM = blockIdx.y * 64, tileN = blockIdx.x * 64;
  const int srow = ln >> 4, pos = ln & 15;

  f32x4 acc[4];
  const f32x4 zf = {0.f, 0.f, 0.f, 0.f};
#pragma unroll
  for (int j = 0; j < 4; ++j) acc[j] = zf;

  int kof[4];
#pragma unroll
  for (int kk = 0; kk < 4; ++kk) {
    int c = kk * 4 + quad;
    kof[kk] = (((c & 8) | ((c & 7) ^ (lq & 7)))) * 8;
  }

  for (int k0 = 0; k0 < 1024; k0 += 128) {
    __syncthreads();
#pragma unroll
    for (int l = 0; l < 4; ++l) {
      int row = l * 16 + wv * 4 + srow;
      int cs = (pos & 8) | ((pos & 7) ^ (row & 7));
      gload_lds16(A + (tileM + row) * 1024 + k0 + cs * 8, &As[(l * 16 + wv * 4) * 128]);
      gload_lds16(Bt + (tileN + row) * 1024 + k0 + cs * 8, &Bs[(l * 16 + wv * 4) * 128]);
    }
    __syncthreads();
#pragma unroll
    for (int kk = 0; kk < 4; ++kk) {
      const int ko = kof[kk];
      bf16x8 af = *(const bf16x8*)&As[(wv * 16 + lq) * 128 + ko];
#pragma unroll
      for (int ni = 0; ni < 4; ++ni) {
        bf16x8 bfr = *(const bf16x8*)&Bs[(ni * 16 + lq) * 128 + ko];
        acc[ni] = __builtin_amdgcn_mfma_f32_16x16x32_bf16(af, bfr, acc[ni], 0, 0, 0);
      }
    }
  }
#pragma unroll
  for (int ni = 0; ni < 4; ++ni) {
    int col = tileN + ni * 16 + lq;
#pragma unroll
    for (int rg = 0; rg < 4; ++rg) {
      int row = tileM + wv * 16 + quad * 4 + rg;
      C[row * 1024 + col] = acc[ni][rg] + bias[col];
    }
  }
}

// ---------------- fused synthesizer attention (in-register P, T12) ----------
// Round-0 pair structure (tiles (p,31-p) share one j-loop, V/W2 double-buffer,
// one barrier/interval), but the P LDS round-trip is GONE:
//   - S computed TRANSPOSED: mfma(w2f, ra) instead of mfma(ra, w2f).  A/B
//     fragments have identical lane layouts for 16x16x32, so the operand swap
//     transposes the output with zero load changes.  Each lane now holds
//     P[j = ni*16+quad*4+rg][token = wv*16+lq] for its ONE token.
//   - PV A-fragment built in registers: per (kk,pr) pair, cvt_pk the even-ni
//     and odd-ni dwords, then v_permlane32_swap + v_permlane16_swap yields
//     BOTH needed output dwords (quad exchange q0<-{0,1}, q1<-{2,3},
//     q2<-{0,1}, q3<-{2,3} with ni = 2kk+(q>>1), verified algebra).
// Deletes per wave per tile: 16 ds_write_b16 + 2 ds_read_b128 + the serial
// exp->store->lgkmcnt->load chain (the LDS pipe was the saturated resource:
// ~4000 LDS-pipe cyc per CU-interval vs ~2500 cyc observed interval).
// LDS 40KB -> 32KB.
__global__ __launch_bounds__(256, 2) void attn(
    const unsigned short* __restrict__ r, const unsigned short* __restrict__ w2t,
    const unsigned short* __restrict__ vt, const unsigned short* __restrict__ ebj,
    unsigned short* __restrict__ y) {
  __shared__ unsigned short W2s[2][64 * 64];
  __shared__ unsigned short Vs[2][64 * 64];

  const int tid = threadIdx.x;
  const int wv = tid >> 6, ln = tid & 63;
  const int quad = ln >> 4, lq = ln & 15;
  const int bh = blockIdx.x, b = bh >> 4, h = bh & 15;
  const int q = blockIdx.y;
  const int p = (q < 8) ? q : 23 - q;             // pair (p, 31-p)
  const int ta = p, tb = 31 - p;
  const int t0a = ta * 64, t0b = tb * 64;
  const int rowL = ln >> 3;
  const int kc = (((ln & 7) ^ rowL) & 7) * 8;
  const int sx = lq & 7;
  const int ko0 = (quad ^ sx) * 8, ko1 = ((4 + quad) ^ sx) * 8;

  // R B-fragments for both tiles (L2-hot)
  bf16x8 ra[2][2];
  {
    const unsigned short* base = r + (b * 2048 + wv * 16 + lq) * 1024 + h * 64 + quad * 8;
    ra[0][0] = *(const bf16x8*)(base + t0a * 1024);
    ra[0][1] = *(const bf16x8*)(base + t0a * 1024 + 32);
    ra[1][0] = *(const bf16x8*)(base + t0b * 1024);
    ra[1][1] = *(const bf16x8*)(base + t0b * 1024 + 32);
  }

  f32x4 accY[2][4];
  f32x4 accL[2];
  const f32x4 zf = {0.f, 0.f, 0.f, 0.f};
#pragma unroll
  for (int s = 0; s < 2; ++s) {
    accL[s] = zf;
#pragma unroll
    for (int nd = 0; nd < 4; ++nd) accY[s][nd] = zf;
  }

  auto stage = [&](int jt, int bi) {
    int j0 = jt * 64;
#pragma unroll
    for (int l = 0; l < 2; ++l) {
      int row = l * 32 + wv * 8 + rowL;
      gload_lds16(w2t + (j0 + row) * 64 + kc, &W2s[bi][l * 2048 + wv * 512]);
      gload_lds16(vt + (h * 64 + row) * 4096 + b * 2048 + j0 + kc,
                  &Vs[bi][l * 2048 + wv * 512]);
    }
  };

#define TILE(S, T0, TT)                                                         \
    {                                                                           \
      f32x4 sv[4];                                                              \
      _Pragma("unroll") for (int ni = 0; ni < 4; ++ni) {                        \
        sv[ni] = __builtin_amdgcn_mfma_f32_16x16x32_bf16(w2f0[ni], ra[S][0], zf, 0, 0, 0); \
        sv[ni] = __builtin_amdgcn_mfma_f32_16x16x32_bf16(w2f1[ni], ra[S][1], sv[ni], 0, 0, 0); \
      }                                                                         \
      const bool diag = (jt == (TT));                                           \
      const int tl = (T0) + wv * 16 + lq;                                       \
      _Pragma("unroll") for (int ni = 0; ni < 4; ++ni)                          \
        _Pragma("unroll") for (int rg = 0; rg < 4; ++rg) {                      \
          float pe = __expf(sv[ni][rg]);                                        \
          if (diag) {                                                           \
            int j = j0 + ni * 16 + quad * 4 + rg;                               \
            pe = (j <= tl) ? pe : 0.f;                                          \
          }                                                                     \
          sv[ni][rg] = pe;                                                      \
        }                                                                       \
      bf16x8 pa0, pa1;                                                          \
      {                                                                         \
        union { unsigned u[4]; bf16x8 v; } k0u, k1u;                            \
        _Pragma("unroll") for (int pr = 0; pr < 2; ++pr) {                      \
          unsigned a0 = cvtpk(sv[0][2 * pr], sv[0][2 * pr + 1]);                \
          unsigned b0 = cvtpk(sv[1][2 * pr], sv[1][2 * pr + 1]);                \
          asm("v_permlane32_swap_b32 %0, %1" : "+v"(a0), "+v"(b0));             \
          asm("v_permlane16_swap_b32 %0, %1" : "+v"(a0), "+v"(b0));             \
          k0u.u[pr] = a0; k0u.u[2 + pr] = b0;                                   \
          unsigned a1 = cvtpk(sv[2][2 * pr], sv[2][2 * pr + 1]);                \
          unsigned b1 = cvtpk(sv[3][2 * pr], sv[3][2 * pr + 1]);                \
          asm("v_permlane32_swap_b32 %0, %1" : "+v"(a1), "+v"(b1));             \
          asm("v_permlane16_swap_b32 %0, %1" : "+v"(a1), "+v"(b1));             \
          k1u.u[pr] = a1; k1u.u[2 + pr] = b1;                                   \
        }                                                                       \
        pa0 = k0u.v; pa1 = k1u.v;                                               \
      }                                                                         \
      _Pragma("unroll") for (int nd = 0; nd < 4; ++nd) {                        \
        bf16x8 bb0 = *(const bf16x8*)&Vs[cb][(nd * 16 + lq) * 64 + ko0];        \
        accY[S][nd] = __builtin_amdgcn_mfma_f32_16x16x32_bf16(pa0, bb0, accY[S][nd], 0, 0, 0); \
        bf16x8 bb1 = *(const bf16x8*)&Vs[cb][(nd * 16 + lq) * 64 + ko1];        \
        accY[S][nd] = __builtin_amdgcn_mfma_f32_16x16x32_bf16(pa1, bb1, accY[S][nd], 0, 0, 0); \
      }                                                                         \
      accL[S] = __builtin_amdgcn_mfma_f32_16x16x32_bf16(pa0, eb0, accL[S], 0, 0, 0); \
      accL[S] = __builtin_amdgcn_mfma_f32_16x16x32_bf16(pa1, eb1, accL[S], 0, 0, 0); \
    }

#define WRITEOUT(S, T0)                                                         \
    {                                                                           \
      float inv[4];                                                             \
      _Pragma("unroll") for (int rg = 0; rg < 4; ++rg)                          \
        inv[rg] = __builtin_amdgcn_rcpf(accL[S][rg]);                           \
      _Pragma("unroll") for (int nd = 0; nd < 4; ++nd)                          \
        _Pragma("unroll") for (int rg = 0; rg < 4; ++rg) {                      \
          int t = (T0) + wv * 16 + quad * 4 + rg;                               \
          y[(b * 2048 + t) * 1024 + h * 64 + nd * 16 + lq] =                    \
              f2bf(accY[S][nd][rg] * inv[rg]);                                  \
        }                                                                       \
    }

  stage(0, 0);
  for (int jt = 0; jt <= tb; ++jt) {
    const int cb = jt & 1;
    __syncthreads();                 // staging(jt) landed; other buf free
    if (jt < tb) stage(jt + 1, cb ^ 1);
    const int j0 = jt * 64;

    // shared per-interval fragments: ebj + W2 (feed both tiles)
    bf16x8 eb0 = *(const bf16x8*)&ebj[j0 + quad * 8];
    bf16x8 eb1 = *(const bf16x8*)&ebj[j0 + 32 + quad * 8];
    bf16x8 w2f0[4], w2f1[4];
#pragma unroll
    for (int ni = 0; ni < 4; ++ni) {
      w2f0[ni] = *(const bf16x8*)&W2s[cb][(ni * 16 + lq) * 64 + ko0];
      w2f1[ni] = *(const bf16x8*)&W2s[cb][(ni * 16 + lq) * 64 + ko1];
    }

    if (jt <= ta) TILE(0, t0a, ta);
    TILE(1, t0b, tb);
    if (jt == ta) WRITEOUT(0, t0a);
  }
  WRITEOUT(1, t0b);
#undef TILE
#undef WRITEOUT
}

// ---------------- launch ----------------
extern "C" void kernel_launch(void* const* d_in, const int* in_sizes, int n_in,
                              void* d_out, int out_size, void* d_ws, size_t ws_size,
                              hipStream_t stream) {
  const float* x  = (const float*)d_in[0];
  const float* W1 = (const float*)d_in[1];
  const float* b1 = (const float*)d_in[2];
  const float* w2 = (const float*)d_in[3];
  const float* b2 = (const float*)d_in[4];
  const float* Wv = (const float*)d_in[5];
  const float* bv = (const float*)d_in[6];
  const float* Wp = (const float*)d_in[7];
  const float* bp = (const float*)d_in[8];

  unsigned short* ws  = (unsigned short*)d_ws;
  unsigned short* xb   = ws;                 // 4096x1024 bf16
  unsigned short* W1b  = ws + 4194304;       // 1024x1024
  unsigned short* Wvb  = ws + 5242880;       // 1024x1024
  unsigned short* Wpb  = ws + 6291456;       // 1024x1024
  unsigned short* w2t  = ws + 7340032;       // 2048x64
  unsigned short* rb   = ws + 7471104;       // 4096x1024
  unsigned short* vt   = ws + 11665408;      // 1024x4096
  unsigned short* yb   = ws + 15859712;      // 4096x1024 bf16
  unsigned short* ebjb = ws + 20054016;      // 2048 bf16

  prep<<<7298, 256, 0, stream>>>(x, W1, Wv, Wp, w2, b2, xb, W1b, Wvb, Wpb, w2t, ebjb);
  gemm_rv<<<dim3(64, 16), 256, 0, stream>>>(xb, W1b, Wvb, b1, bv, b2, rb, vt);
  attn<<<dim3(32, 16), 256, 0, stream>>>(rb, w2t, vt, ebjb, yb);
  gemm_p<<<dim3(16, 64), 256, 0, stream>>>(yb, Wpb, bp, (float*)d_out);
}

// Round 3
// 166.259 us; speedup vs baseline: 1.0757x; 1.0032x over previous
//
#include <hip/hip_runtime.h>

typedef __bf16 bf16x8 __attribute__((ext_vector_type(8)));
typedef float f32x4 __attribute__((ext_vector_type(4)));
typedef float f32x16 __attribute__((ext_vector_type(16)));

__device__ __forceinline__ unsigned short f2bf(float f) {
  union { float f; unsigned u; } v; v.f = f;
  unsigned u = v.u;
  return (unsigned short)((u + 0x7fffu + ((u >> 16) & 1u)) >> 16);  // RNE
}
__device__ __forceinline__ void gload_lds16(const void* g, void* l) {
  __builtin_amdgcn_global_load_lds(
      (const __attribute__((address_space(1))) unsigned int*)g,
      (__attribute__((address_space(3))) unsigned int*)l, 16, 0, 0);
}
__device__ __forceinline__ unsigned cvtpk(float lo, float hi) {
  unsigned r;
  asm("v_cvt_pk_bf16_f32 %0, %1, %2" : "=v"(r) : "v"(lo), "v"(hi));
  return r;
}
__device__ __forceinline__ void cvt4(const float* __restrict__ s,
                                     unsigned short* __restrict__ d, int u) {
  f32x4 v = ((const f32x4*)s)[u];
  union { unsigned short s[4]; unsigned long long u; } o;
  o.s[0] = f2bf(v[0]); o.s[1] = f2bf(v[1]); o.s[2] = f2bf(v[2]); o.s[3] = f2bf(v[3]);
  ((unsigned long long*)d)[u] = o.u;
}

// LDS tile swizzle (128B rows): row r, 16B-chunk c stored at position c^(r&7).
// Staging lane fetches global chunk (ln&7)^(ln>>3); reads XOR chunk with r&7.
// For 256B rows (BK=128): chunk c (0..15) at position (c&8)|((c&7)^(r&7)).

// ---------------- prep: f32->bf16 conversions + ebj, one launch -------------
__global__ void prep(const float* __restrict__ x, const float* __restrict__ W1,
                     const float* __restrict__ Wv, const float* __restrict__ Wp,
                     const float* __restrict__ w2, const float* __restrict__ b2,
                     unsigned short* __restrict__ xb, unsigned short* __restrict__ W1b,
                     unsigned short* __restrict__ Wvb, unsigned short* __restrict__ Wpb,
                     unsigned short* __restrict__ w2t, unsigned short* __restrict__ ebj) {
  int u = blockIdx.x * 256 + threadIdx.x;
  if (u < 1048576) { cvt4(x, xb, u); return; }
  u -= 1048576;
  if (u < 262144) { cvt4(W1, W1b, u); return; }
  u -= 262144;
  if (u < 262144) { cvt4(Wv, Wvb, u); return; }
  u -= 262144;
  if (u < 262144) { cvt4(Wp, Wpb, u); return; }
  u -= 262144;
  if (u < 32768) {
    // w2 (64,2048) f32 -> w2t (2048,64) bf16
    int j = u >> 4, d4 = (u & 15) * 4;
    union { unsigned short s[4]; unsigned long long x; } o;
#pragma unroll
    for (int i = 0; i < 4; ++i) o.s[i] = f2bf(w2[(d4 + i) * 2048 + j]);
    ((unsigned long long*)w2t)[u] = o.x;
    return;
  }
  u -= 32768;
  // ebj = bf16(exp(b2)), 2048 elems in 512 x4-units
  union { unsigned short s[4]; unsigned long long x; } o;
#pragma unroll
  for (int i = 0; i < 4; ++i) o.s[i] = f2bf(__expf(b2[u * 4 + i]));
  ((unsigned long long*)ebj)[u] = o.x;
}

// ---------------- fused r & vt GEMM: 32x32 MFMA, shared-X fragments ---------
// 64x64 block tile, 4 waves, each wave owns 32 tokens x 32 chans of R AND the
// transposed 32 chans x 32 tokens of V over the SAME token set, so one X
// fragment read serves as R's A-operand and V's B-operand (A/B lane layouts
// identical for 32x32x16).  Per wave per K-step: 12 ds_read_b128 + 8 MFMA
// (was 20 + 16 with 16x16x32).  Grid/LDS/occupancy unchanged (24KB, 4/CU).
__global__ __launch_bounds__(256) void gemm_rv(
    const unsigned short* __restrict__ xb, const unsigned short* __restrict__ W1b,
    const unsigned short* __restrict__ Wvb, const float* __restrict__ b1,
    const float* __restrict__ bv, const float* __restrict__ b2,
    unsigned short* __restrict__ rb, unsigned short* __restrict__ vtb) {
  __shared__ unsigned short Xs[64 * 64];
  __shared__ unsigned short W1s[64 * 64];
  __shared__ unsigned short Wvs[64 * 64];
  const int tm = blockIdx.x * 64, n0 = blockIdx.y * 64;
  const int tid = threadIdx.x;
  const int wv = tid >> 6, ln = tid & 63;
  const int l5 = ln >> 5, l31 = ln & 31;
  const int tw = (wv & 1) * 32;      // token base within tile
  const int cw = (wv >> 1) * 32;     // chan base within tile
  const int rowL = ln >> 3;
  const int kc = (((ln & 7) ^ rowL) & 7) * 8;

  // per-kk swizzled LDS offsets (chunk c = kk*2 + l5, row&7 == l31&7)
  int xoff[4], woff[4];
#pragma unroll
  for (int kk = 0; kk < 4; ++kk) {
    int c = kk * 2 + l5;
    int p = (c ^ (l31 & 7)) * 8;
    xoff[kk] = (tw + l31) * 64 + p;
    woff[kk] = (cw + l31) * 64 + p;
  }

  f32x16 accR, accV;
#pragma unroll
  for (int i = 0; i < 16; ++i) { accR[i] = 0.f; accV[i] = 0.f; }

  for (int k0 = 0; k0 < 1024; k0 += 64) {
    __syncthreads();
#pragma unroll
    for (int l = 0; l < 2; ++l) {
      int row = l * 32 + wv * 8 + rowL;
      gload_lds16(xb + (tm + row) * 1024 + k0 + kc, &Xs[l * 2048 + wv * 512]);
      gload_lds16(W1b + (n0 + row) * 1024 + k0 + kc, &W1s[l * 2048 + wv * 512]);
      gload_lds16(Wvb + (n0 + row) * 1024 + k0 + kc, &Wvs[l * 2048 + wv * 512]);
    }
    __syncthreads();
#pragma unroll
    for (int kk = 0; kk < 4; ++kk) {
      bf16x8 xa  = *(const bf16x8*)&Xs[xoff[kk]];
      bf16x8 w1f = *(const bf16x8*)&W1s[woff[kk]];
      bf16x8 wvf = *(const bf16x8*)&Wvs[woff[kk]];
      accR = __builtin_amdgcn_mfma_f32_32x32x16_bf16(xa, w1f, accR, 0, 0, 0);
      accV = __builtin_amdgcn_mfma_f32_32x32x16_bf16(wvf, xa, accV, 0, 0, 0);
    }
  }
  // epilogue R: token row = tm+tw+rr, chan col = n0+cw+l31
  {
    int col = n0 + cw + l31;
    float bc = b1[col];
#pragma unroll
    for (int r = 0; r < 16; ++r) {
      int rr = (r & 3) + 8 * (r >> 2) + 4 * l5;
      float v = accR[r] + bc;
      rb[(tm + tw + rr) * 1024 + col] = f2bf(v > 0.f ? v : 0.f);
    }
  }
  // epilogue V: chan row = n0+cw+rr, token col = tm+tw+l31
  {
    int tok = tm + tw + l31;
    float eb = __expf(b2[tok & 2047]);
#pragma unroll
    for (int r = 0; r < 16; ++r) {
      int rr = (r & 3) + 8 * (r >> 2) + 4 * l5;
      int ch = n0 + cw + rr;
      vtb[ch * 4096 + tok] = f2bf((accV[r] + bv[ch]) * eb);
    }
  }
}

// ---------------- final GEMM: d_out = yb @ Wp^T + bp (f32 out) --------------
// 64x64 block, 4 waves in 2x2, each one 32x32 acc via 32x32x16 MFMA.
// Per wave per K-step(128): 16 ds_read_b128 + 8 MFMA (was 20 + 16).
// LDS 32KB, grid (16,64)=1024 blocks = 4/CU -- unchanged.
__global__ __launch_bounds__(256) void gemm_p(
    const unsigned short* __restrict__ A, const unsigned short* __restrict__ Bt,
    const float* __restrict__ bias, float* __restrict__ C) {
  __shared__ unsigned short As[64 * 128];
  __shared__ unsigned short Bs[64 * 128];
  const int tid = threadIdx.x;
  const int wv = tid >> 6, ln = tid & 63;
  const int l5 = ln >> 5, l31 = ln & 31;
  const int wm = (wv & 1) * 32, wn = (wv >> 1) * 32;
  const int tileM = blockIdx.y * 64, tileN = blockIdx.x * 64;
  const int srow = ln >> 4, pos = ln & 15;

  // per-kk swizzled offsets: 256B rows, chunk c at (c&8)|((c&7)^(row&7))
  int aoff[8], boff[8];
#pragma unroll
  for (int kk = 0; kk < 8; ++kk) {
    int c = kk * 2 + l5;
    int p = ((c & 8) | ((c & 7) ^ (l31 & 7))) * 8;
    aoff[kk] = (wm + l31) * 128 + p;
    boff[kk] = (wn + l31) * 128 + p;
  }

  f32x16 acc;
#pragma unroll
  for (int i = 0; i < 16; ++i) acc[i] = 0.f;

  for (int k0 = 0; k0 < 1024; k0 += 128) {
    __syncthreads();
#pragma unroll
    for (int l = 0; l < 4; ++l) {
      int row = l * 16 + wv * 4 + srow;
      int cs = (pos & 8) | ((pos & 7) ^ (row & 7));
      gload_lds16(A + (tileM + row) * 1024 + k0 + cs * 8, &As[(l * 16 + wv * 4) * 128]);
      gload_lds16(Bt + (tileN + row) * 1024 + k0 + cs * 8, &Bs[(l * 16 + wv * 4) * 128]);
    }
    __syncthreads();
#pragma unroll
    for (int kk = 0; kk < 8; ++kk) {
      bf16x8 af  = *(const bf16x8*)&As[aoff[kk]];
      bf16x8 bfr = *(const bf16x8*)&Bs[boff[kk]];
      acc = __builtin_amdgcn_mfma_f32_32x32x16_bf16(af, bfr, acc, 0, 0, 0);
    }
  }
#pragma unroll
  for (int r = 0; r < 16; ++r) {
    int rr = (r & 3) + 8 * (r >> 2) + 4 * l5;
    int row = tileM + wm + rr;
    int col = tileN + wn + l31;
    C[row * 1024 + col] = acc[r] + bias[col];
  }
}

// ---------------- fused synthesizer attention (in-register P, T12) ----------
// Round-0 pair structure (tiles (p,31-p) share one j-loop, V/W2 double-buffer,
// one barrier/interval), but the P LDS round-trip is GONE:
//   - S computed TRANSPOSED: mfma(w2f, ra) instead of mfma(ra, w2f).  A/B
//     fragments have identical lane layouts for 16x16x32, so the operand swap
//     transposes the output with zero load changes.  Each lane now holds
//     P[j = ni*16+quad*4+rg][token = wv*16+lq] for its ONE token.
//   - PV A-fragment built in registers: per (kk,pr) pair, cvt_pk the even-ni
//     and odd-ni dwords, then v_permlane32_swap + v_permlane16_swap yields
//     BOTH needed output dwords.
__global__ __launch_bounds__(256, 2) void attn(
    const unsigned short* __restrict__ r, const unsigned short* __restrict__ w2t,
    const unsigned short* __restrict__ vt, const unsigned short* __restrict__ ebj,
    unsigned short* __restrict__ y) {
  __shared__ unsigned short W2s[2][64 * 64];
  __shared__ unsigned short Vs[2][64 * 64];

  const int tid = threadIdx.x;
  const int wv = tid >> 6, ln = tid & 63;
  const int quad = ln >> 4, lq = ln & 15;
  const int bh = blockIdx.x, b = bh >> 4, h = bh & 15;
  const int q = blockIdx.y;
  const int p = (q < 8) ? q : 23 - q;             // pair (p, 31-p)
  const int ta = p, tb = 31 - p;
  const int t0a = ta * 64, t0b = tb * 64;
  const int rowL = ln >> 3;
  const int kc = (((ln & 7) ^ rowL) & 7) * 8;
  const int sx = lq & 7;
  const int ko0 = (quad ^ sx) * 8, ko1 = ((4 + quad) ^ sx) * 8;

  // R B-fragments for both tiles (L2-hot)
  bf16x8 ra[2][2];
  {
    const unsigned short* base = r + (b * 2048 + wv * 16 + lq) * 1024 + h * 64 + quad * 8;
    ra[0][0] = *(const bf16x8*)(base + t0a * 1024);
    ra[0][1] = *(const bf16x8*)(base + t0a * 1024 + 32);
    ra[1][0] = *(const bf16x8*)(base + t0b * 1024);
    ra[1][1] = *(const bf16x8*)(base + t0b * 1024 + 32);
  }

  f32x4 accY[2][4];
  f32x4 accL[2];
  const f32x4 zf = {0.f, 0.f, 0.f, 0.f};
#pragma unroll
  for (int s = 0; s < 2; ++s) {
    accL[s] = zf;
#pragma unroll
    for (int nd = 0; nd < 4; ++nd) accY[s][nd] = zf;
  }

  auto stage = [&](int jt, int bi) {
    int j0 = jt * 64;
#pragma unroll
    for (int l = 0; l < 2; ++l) {
      int row = l * 32 + wv * 8 + rowL;
      gload_lds16(w2t + (j0 + row) * 64 + kc, &W2s[bi][l * 2048 + wv * 512]);
      gload_lds16(vt + (h * 64 + row) * 4096 + b * 2048 + j0 + kc,
                  &Vs[bi][l * 2048 + wv * 512]);
    }
  };

#define TILE(S, T0, TT)                                                         \
    {                                                                           \
      f32x4 sv[4];                                                              \
      _Pragma("unroll") for (int ni = 0; ni < 4; ++ni) {                        \
        sv[ni] = __builtin_amdgcn_mfma_f32_16x16x32_bf16(w2f0[ni], ra[S][0], zf, 0, 0, 0); \
        sv[ni] = __builtin_amdgcn_mfma_f32_16x16x32_bf16(w2f1[ni], ra[S][1], sv[ni], 0, 0, 0); \
      }                                                                         \
      const bool diag = (jt == (TT));                                           \
      const int tl = (T0) + wv * 16 + lq;                                       \
      _Pragma("unroll") for (int ni = 0; ni < 4; ++ni)                          \
        _Pragma("unroll") for (int rg = 0; rg < 4; ++rg) {                      \
          float pe = __expf(sv[ni][rg]);                                        \
          if (diag) {                                                           \
            int j = j0 + ni * 16 + quad * 4 + rg;                               \
            pe = (j <= tl) ? pe : 0.f;                                          \
          }                                                                     \
          sv[ni][rg] = pe;                                                      \
        }                                                                       \
      bf16x8 pa0, pa1;                                                          \
      {                                                                         \
        union { unsigned u[4]; bf16x8 v; } k0u, k1u;                            \
        _Pragma("unroll") for (int pr = 0; pr < 2; ++pr) {                      \
          unsigned a0 = cvtpk(sv[0][2 * pr], sv[0][2 * pr + 1]);                \
          unsigned b0 = cvtpk(sv[1][2 * pr], sv[1][2 * pr + 1]);                \
          asm("v_permlane32_swap_b32 %0, %1" : "+v"(a0), "+v"(b0));             \
          asm("v_permlane16_swap_b32 %0, %1" : "+v"(a0), "+v"(b0));             \
          k0u.u[pr] = a0; k0u.u[2 + pr] = b0;                                   \
          unsigned a1 = cvtpk(sv[2][2 * pr], sv[2][2 * pr + 1]);                \
          unsigned b1 = cvtpk(sv[3][2 * pr], sv[3][2 * pr + 1]);                \
          asm("v_permlane32_swap_b32 %0, %1" : "+v"(a1), "+v"(b1));             \
          asm("v_permlane16_swap_b32 %0, %1" : "+v"(a1), "+v"(b1));             \
          k1u.u[pr] = a1; k1u.u[2 + pr] = b1;                                   \
        }                                                                       \
        pa0 = k0u.v; pa1 = k1u.v;                                               \
      }                                                                         \
      _Pragma("unroll") for (int nd = 0; nd < 4; ++nd) {                        \
        bf16x8 bb0 = *(const bf16x8*)&Vs[cb][(nd * 16 + lq) * 64 + ko0];        \
        accY[S][nd] = __builtin_amdgcn_mfma_f32_16x16x32_bf16(pa0, bb0, accY[S][nd], 0, 0, 0); \
        bf16x8 bb1 = *(const bf16x8*)&Vs[cb][(nd * 16 + lq) * 64 + ko1];        \
        accY[S][nd] = __builtin_amdgcn_mfma_f32_16x16x32_bf16(pa1, bb1, accY[S][nd], 0, 0, 0); \
      }                                                                         \
      accL[S] = __builtin_amdgcn_mfma_f32_16x16x32_bf16(pa0, eb0, accL[S], 0, 0, 0); \
      accL[S] = __builtin_amdgcn_mfma_f32_16x16x32_bf16(pa1, eb1, accL[S], 0, 0, 0); \
    }

#define WRITEOUT(S, T0)                                                         \
    {                                                                           \
      float inv[4];                                                             \
      _Pragma("unroll") for (int rg = 0; rg < 4; ++rg)                          \
        inv[rg] = __builtin_amdgcn_rcpf(accL[S][rg]);                           \
      _Pragma("unroll") for (int nd = 0; nd < 4; ++nd)                          \
        _Pragma("unroll") for (int rg = 0; rg < 4; ++rg) {                      \
          int t = (T0) + wv * 16 + quad * 4 + rg;                               \
          y[(b * 2048 + t) * 1024 + h * 64 + nd * 16 + lq] =                    \
              f2bf(accY[S][nd][rg] * inv[rg]);                                  \
        }                                                                       \
    }

  stage(0, 0);
  for (int jt = 0; jt <= tb; ++jt) {
    const int cb = jt & 1;
    __syncthreads();                 // staging(jt) landed; other buf free
    if (jt < tb) stage(jt + 1, cb ^ 1);
    const int j0 = jt * 64;

    // shared per-interval fragments: ebj + W2 (feed both tiles)
    bf16x8 eb0 = *(const bf16x8*)&ebj[j0 + quad * 8];
    bf16x8 eb1 = *(const bf16x8*)&ebj[j0 + 32 + quad * 8];
    bf16x8 w2f0[4], w2f1[4];
#pragma unroll
    for (int ni = 0; ni < 4; ++ni) {
      w2f0[ni] = *(const bf16x8*)&W2s[cb][(ni * 16 + lq) * 64 + ko0];
      w2f1[ni] = *(const bf16x8*)&W2s[cb][(ni * 16 + lq) * 64 + ko1];
    }

    if (jt <= ta) TILE(0, t0a, ta);
    TILE(1, t0b, tb);
    if (jt == ta) WRITEOUT(0, t0a);
  }
  WRITEOUT(1, t0b);
#undef TILE
#undef WRITEOUT
}

// ---------------- launch ----------------
extern "C" void kernel_launch(void* const* d_in, const int* in_sizes, int n_in,
                              void* d_out, int out_size, void* d_ws, size_t ws_size,
                              hipStream_t stream) {
  const float* x  = (const float*)d_in[0];
  const float* W1 = (const float*)d_in[1];
  const float* b1 = (const float*)d_in[2];
  const float* w2 = (const float*)d_in[3];
  const float* b2 = (const float*)d_in[4];
  const float* Wv = (const float*)d_in[5];
  const float* bv = (const float*)d_in[6];
  const float* Wp = (const float*)d_in[7];
  const float* bp = (const float*)d_in[8];

  unsigned short* ws  = (unsigned short*)d_ws;
  unsigned short* xb   = ws;                 // 4096x1024 bf16
  unsigned short* W1b  = ws + 4194304;       // 1024x1024
  unsigned short* Wvb  = ws + 5242880;       // 1024x1024
  unsigned short* Wpb  = ws + 6291456;       // 1024x1024
  unsigned short* w2t  = ws + 7340032;       // 2048x64
  unsigned short* rb   = ws + 7471104;       // 4096x1024
  unsigned short* vt   = ws + 11665408;      // 1024x4096
  unsigned short* yb   = ws + 15859712;      // 4096x1024 bf16
  unsigned short* ebjb = ws + 20054016;      // 2048 bf16

  prep<<<7298, 256, 0, stream>>>(x, W1, Wv, Wp, w2, b2, xb, W1b, Wvb, Wpb, w2t, ebjb);
  gemm_rv<<<dim3(64, 16), 256, 0, stream>>>(xb, W1b, Wvb, b1, bv, b2, rb, vt);
  attn<<<dim3(32, 16), 256, 0, stream>>>(rb, w2t, vt, ebjb, yb);
  gemm_p<<<dim3(16, 64), 256, 0, stream>>>(yb, Wpb, bp, (float*)d_out);
}